// Round 1
// baseline (1308.473 us; speedup 1.0000x reference)
//
#include <hip/hip_runtime.h>
#include <stdint.h>

#define EPS 1e-8f

// Map float to unsigned such that unsigned order == float order.
__device__ __forceinline__ uint32_t order_f32(float f) {
    uint32_t u = __float_as_uint(f);
    return (u & 0x80000000u) ? ~u : (u | 0x80000000u);
}

// One row (256 fp32 = 1024B) per wave per iteration: lane i loads float4 at
// byte offset 16*i -> wave covers exactly one contiguous row (perfect coalesce).
__global__ __launch_bounds__(256) void sim_argmax_kernel(
    const float* __restrict__ q,
    const float* __restrict__ S,
    unsigned long long* __restrict__ best_packed,
    int N)
{
    const int lane = threadIdx.x & 63;
    const int wave_in_block = threadIdx.x >> 6;
    const int gwave = blockIdx.x * (blockDim.x >> 6) + wave_in_block;
    const int nwaves = gridDim.x * (blockDim.x >> 6);

    // Each lane's fixed segment of q (4 floats), held in registers.
    const float4 q4 = ((const float4*)q)[lane];

    // ||q||^2 reduced across the wave (once).
    float q2 = q4.x * q4.x + q4.y * q4.y + q4.z * q4.z + q4.w * q4.w;
    #pragma unroll
    for (int off = 32; off; off >>= 1) q2 += __shfl_xor(q2, off, 64);
    const float qden = sqrtf(q2) + EPS;

    unsigned long long best = 0ull;

    for (int row = gwave; row < N; row += nwaves) {
        const float4 e4 = ((const float4*)(S + (size_t)row * 256))[lane];
        float d = e4.x * q4.x + e4.y * q4.y + e4.z * q4.z + e4.w * q4.w;
        float n = e4.x * e4.x + e4.y * e4.y + e4.z * e4.z + e4.w * e4.w;
        #pragma unroll
        for (int off = 32; off; off >>= 1) {
            d += __shfl_xor(d, off, 64);
            n += __shfl_xor(n, off, 64);
        }
        const float sim = d / ((sqrtf(n) + EPS) * qden);
        // Pack: high 32 = orderable score (bigger = better), low 32 = ~row so
        // that on score tie the SMALLER row index wins (matches jnp.argmax).
        const unsigned long long pk =
            ((unsigned long long)order_f32(sim) << 32) | (uint32_t)(~(uint32_t)row);
        if (pk > best) best = pk;
    }

    // After the butterfly all 64 lanes hold identical (d,n) -> identical best.
    if (lane == 0 && best) {
        atomicMax(best_packed, best);  // device-scope by default on CDNA
    }
}

__global__ void finalize_kernel(const unsigned long long* __restrict__ best_packed,
                                float* __restrict__ out)
{
    const unsigned long long p = *best_packed;
    const uint32_t ord = (uint32_t)(p >> 32);
    const uint32_t bits = (ord & 0x80000000u) ? (ord ^ 0x80000000u) : ~ord;
    const uint32_t idx = ~(uint32_t)(p & 0xFFFFFFFFu);
    out[0] = (float)idx;            // best_match index (exact: < 2^24)
    out[1] = __uint_as_float(bits); // best_score
}

extern "C" void kernel_launch(void* const* d_in, const int* in_sizes, int n_in,
                              void* d_out, int out_size, void* d_ws, size_t ws_size,
                              hipStream_t stream) {
    const float* q = (const float*)d_in[0];
    const float* S = (const float*)d_in[1];
    const int N = in_sizes[1] / 256;

    unsigned long long* best_packed = (unsigned long long*)d_ws;

    // ws is re-poisoned to 0xAA before every timed launch -> must re-zero.
    hipMemsetAsync(best_packed, 0, sizeof(unsigned long long), stream);

    // 2048 blocks x 256 threads = 8192 waves = 32 waves/CU on 256 CUs.
    sim_argmax_kernel<<<2048, 256, 0, stream>>>(q, S, best_packed, N);

    finalize_kernel<<<1, 1, 0, stream>>>(best_packed, (float*)d_out);
}